// Round 7
// baseline (551.322 us; speedup 1.0000x reference)
//
#include <hip/hip_runtime.h>
#include <cstdint>
#include <cstddef>

// ---------------------------------------------------------------------------
// BatchTreeEncoder on MFMA: A=4, D=7, B=64, E=128, H=128, N_NODES=5461
// R7: fused kernel latency fixes: (1) parent-x read direct from emb in phase D
// (xs LDS deleted; 64-row set is L1-resident across waves), (2) LDS 59392 ->
// 43008 B => 3 blocks/CU, (3) register prefetch of child a+1 during child a's
// MFMA+tanh. Subtree-max P recursion as in R6. 9 dispatches.
// ---------------------------------------------------------------------------

typedef short  bf16x8 __attribute__((ext_vector_type(8)));
typedef float  f32x4  __attribute__((ext_vector_type(4)));

// workspace layout (bytes)
#define WS_WIH   0u                        // 384*128*2
#define WS_WHH   (WS_WIH + 98304u)
#define WS_SWT   (WS_WHH + 98304u)         // 128*128*2
#define WS_EMB   (WS_SWT + 32768u)         // 50000*128*2 = 12.8 MB
#define WS_P     (WS_EMB + 12800000u)      // 1365*8192*2 = 22.4 MB (inner P)
#define WS_H     (WS_P + 22364160u)        // 5461*8192*2 = 89.5 MB
// total ~124.6 MB

__device__ __forceinline__ float sigm(float x)   { return 1.0f / (1.0f + __expf(-x)); }
__device__ __forceinline__ float sigmc(float x)  { return 1.0f / (1.0f + __expf(x)); }   // 1-sigm
__device__ __forceinline__ float tanhf_(float x) { return 1.0f - 2.0f / (1.0f + __expf(2.0f * x)); }

__device__ __forceinline__ unsigned short f2b(float f) {
  unsigned u = __float_as_uint(f);
  u += 0x7fffu + ((u >> 16) & 1u);     // RNE (no NaN here)
  return (unsigned short)(u >> 16);
}
__device__ __forceinline__ float b2f(unsigned short s) {
  return __uint_as_float(((unsigned)s) << 16);
}

__device__ __forceinline__ f32x4 mfma16(bf16x8 a, bf16x8 b, f32x4 c) {
  return __builtin_amdgcn_mfma_f32_16x16x32_bf16(a, b, c, 0, 0, 0);
}

// P[root] is the final (64,128) max in bf16
__global__ __launch_bounds__(256) void decode_out(const unsigned short* __restrict__ P0,
                                                  float* __restrict__ out) {
  int i = blockIdx.x * 256 + threadIdx.x;              // grid 32
  out[i] = b2f(P0[i]);
}

// merged prep: emb fp32->bf16 (first 6250 blocks), weights + swT (last 448)
__global__ __launch_bounds__(256) void prep_all(const float* __restrict__ emb,
                                                const float* __restrict__ wih,
                                                const float* __restrict__ whh,
                                                const float* __restrict__ sw,
                                                unsigned short* __restrict__ embb,
                                                unsigned short* __restrict__ wihb,
                                                unsigned short* __restrict__ whhb,
                                                unsigned short* __restrict__ swtb) {
  int i = blockIdx.x * 256 + threadIdx.x;              // grid 6698
  if (i < 1600000) {                                   // 1.6M float4s of emb
    float4 v = *(const float4*)(emb + (size_t)i * 4);
    ushort4 o; o.x = f2b(v.x); o.y = f2b(v.y); o.z = f2b(v.z); o.w = f2b(v.w);
    *(ushort4*)(embb + (size_t)i * 4) = o;
  } else {
    int j = i - 1600000;                               // 0..114687
    if (j < 49152)       wihb[j] = f2b(wih[j]);
    else if (j < 98304)  whhb[j - 49152] = f2b(whh[j - 49152]);
    else { int k = j - 98304; int ku = k >> 7; int h = k & 127; swtb[k] = f2b(sw[h * 128 + ku]); }
  }
}

// ---------------------------------------------------------------------------
// Leaf GRU (h0 = 0): grid 4096, block 512 (8 waves). Wave w owns j = w*16+l.
// Epilogue through LDS (stride 136) -> dwordx4 stores.
// ---------------------------------------------------------------------------
__global__ __launch_bounds__(512, 2) void gru_leaf(
    const int*            __restrict__ tok,
    const unsigned short* __restrict__ embb,
    const unsigned short* __restrict__ wih,
    const float*          __restrict__ b_ih,
    const float*          __restrict__ b_hh,
    unsigned short*       __restrict__ hout)
{
  __shared__ unsigned short xs[8192];
  __shared__ unsigned short hvb[64 * 136];

  const int node = blockIdx.x;
  const int t = threadIdx.x;

  {
    const int* tp = tok + node * 64;
#pragma unroll
    for (int i = 0; i < 2; ++i) {
      int g = t + 512 * i;
      int m = g >> 4, c = g & 15;
      uint4 v = *(const uint4*)(embb + (size_t)tp[m] * 128 + c * 8);
      *(uint4*)(xs + m * 128 + ((c ^ (m & 15)) << 3)) = v;
    }
  }

  const int w = __builtin_amdgcn_readfirstlane(t >> 6);
  const int lane = t & 63, l = lane & 15, q = lane >> 4;
  const int j = w * 16 + l;

  bf16x8 Br[4], Bz[4], Bn[4];
#pragma unroll
  for (int ks = 0; ks < 4; ++ks) {
    const int ko = ks * 32 + q * 8;
    Br[ks] = *(const bf16x8*)(wih + (size_t)j * 128 + ko);
    Bz[ks] = *(const bf16x8*)(wih + (size_t)(128 + j) * 128 + ko);
    Bn[ks] = *(const bf16x8*)(wih + (size_t)(256 + j) * 128 + ko);
  }

  f32x4 Cr[4] = {}, Cz[4] = {}, Cn[4] = {};
  __syncthreads();

#pragma unroll
  for (int ks = 0; ks < 4; ++ks) {
    bf16x8 A[4];
#pragma unroll
    for (int mt = 0; mt < 4; ++mt) {
      int m = mt * 16 + l, c = ks * 4 + q;
      A[mt] = *(const bf16x8*)(xs + m * 128 + (((c ^ l) & 15) << 3));
    }
#pragma unroll
    for (int mt = 0; mt < 4; ++mt) {
      Cr[mt] = mfma16(A[mt], Br[ks], Cr[mt]);
      Cz[mt] = mfma16(A[mt], Bz[ks], Cz[mt]);
      Cn[mt] = mfma16(A[mt], Bn[ks], Cn[mt]);
    }
  }

  const float bR = b_ih[j] + b_hh[j];
  const float bZ = b_ih[128 + j] + b_hh[128 + j];
  const float bN = b_ih[256 + j];
  const float bH = b_hh[256 + j];

#pragma unroll
  for (int mt = 0; mt < 4; ++mt) {
#pragma unroll
    for (int e = 0; e < 4; ++e) {
      const int b = mt * 16 + q * 4 + e;
      float r  = sigm(Cr[mt][e] + bR);
      float zc = sigmc(Cz[mt][e] + bZ);
      float nv = tanhf_(Cn[mt][e] + bN + r * bH);
      hvb[b * 136 + j] = f2b(zc * nv);           // hp = 0
    }
  }
  __syncthreads();

#pragma unroll
  for (int i = 0; i < 2; ++i) {
    int g = t + 512 * i;
    int m = g >> 4, c = g & 15;
    uint4 v = *(const uint4*)(hvb + m * 136 + c * 8);
    *(uint4*)(hout + (size_t)(node * 64 + m) * 128 + c * 8) = v;
  }
}

// ---------------------------------------------------------------------------
// Fused attention + GRU + subtree-max for one inner level. grid = n parents,
// block 512. Child slabs register-prefetched one iteration ahead; parent-x
// A-frags read direct from emb (no xs buffer). LDS 43008 B -> 3 blocks/CU.
// ---------------------------------------------------------------------------
template <bool LEAF_CHILD>
__global__ __launch_bounds__(512, 6) void fused_attn_gru(
    const unsigned short* __restrict__ hch,   // children h base
    const unsigned short* __restrict__ Pch,   // children P base (unused if LEAF_CHILD)
    const int*            __restrict__ tok,
    const unsigned short* __restrict__ embb,
    const unsigned short* __restrict__ wih,
    const unsigned short* __restrict__ whh,
    const unsigned short* __restrict__ swt,
    const float*          __restrict__ sb,
    const float*          __restrict__ ctx,
    const float*          __restrict__ b_ih,
    const float*          __restrict__ b_hh,
    unsigned short*       __restrict__ hout,
    unsigned short*       __restrict__ Pout)
{
  __shared__ unsigned short chv[64 * 136];  // child slab (stride 128) / hv transpose (136)
  __shared__ unsigned short hs[8192];       // h0 (gru-ready swizzle)
  __shared__ float spart[8][256];
  __shared__ float alf[256];

  const int p = blockIdx.x;
  const int t = threadIdx.x;
  const int w = __builtin_amdgcn_readfirstlane(t >> 6);
  const int lane = t & 63, l = lane & 15, q = lane >> 4;

  // running subtree max per (b,c) staging slot
  float rm[2][8];
#pragma unroll
  for (int k = 0; k < 8; ++k) { rm[0][k] = -3.0e38f; rm[1][k] = -3.0e38f; }

  // parent token rows for phase D (issued early; 4 VGPRs)
  int tokm[4];
#pragma unroll
  for (int mt = 0; mt < 4; ++mt) tokm[mt] = tok[p * 64 + mt * 16 + l];

  bf16x8 Bs[4];
#pragma unroll
  for (int ks = 0; ks < 4; ++ks)
    Bs[ks] = *(const bf16x8*)(swt + (size_t)(w * 16 + l) * 128 + ks * 32 + q * 8);
  const float sbk = sb[w * 16 + l], cxk = ctx[w * 16 + l];

  // staging geometry: thread covers rows m0 and m0+32, chunk c0
  const int m0 = t >> 4, c0 = t & 15;
  const int sw0 = (c0 ^ (m0 & 15)) << 3;    // same for m0+32 (32 = 0 mod 16)
  const unsigned short* ch_base = hch + (size_t)(4 * p) * 8192;

  // prefetch child 0 into registers
  uint4 pre0 = *(const uint4*)(ch_base + m0 * 128 + c0 * 8);
  uint4 pre1 = *(const uint4*)(ch_base + (m0 + 32) * 128 + c0 * 8);

  // phase A: per-child u MFMA + s partials, next child prefetched in regs
  for (int a = 0; a < 4; ++a) {
    if (a) __syncthreads();                  // prev child's MFMA readers done
    *(uint4*)(chv + m0 * 128 + sw0) = pre0;
    *(uint4*)(chv + (m0 + 32) * 128 + sw0) = pre1;
    if constexpr (LEAF_CHILD) {              // leaf child: P = h, fold at staging
      const unsigned short* e0 = (const unsigned short*)&pre0;
      const unsigned short* e1 = (const unsigned short*)&pre1;
#pragma unroll
      for (int k = 0; k < 8; ++k) {
        rm[0][k] = fmaxf(rm[0][k], b2f(e0[k]));
        rm[1][k] = fmaxf(rm[1][k], b2f(e1[k]));
      }
    }
    if (a < 3) {                             // issue next child's loads now;
      const unsigned short* nsrc = ch_base + (size_t)(a + 1) * 8192;
      pre0 = *(const uint4*)(nsrc + m0 * 128 + c0 * 8);
      pre1 = *(const uint4*)(nsrc + (m0 + 32) * 128 + c0 * 8);
    }                                        // waitcnt lands at next iter's write
    __syncthreads();

    f32x4 Cu[4] = {};
#pragma unroll
    for (int ks = 0; ks < 4; ++ks) {
#pragma unroll
      for (int mt = 0; mt < 4; ++mt) {
        int m = mt * 16 + l, c = ks * 4 + q;
        bf16x8 A = *(const bf16x8*)(chv + m * 128 + (((c ^ l) & 15) << 3));
        Cu[mt] = mfma16(A, Bs[ks], Cu[mt]);
      }
    }
#pragma unroll
    for (int mt = 0; mt < 4; ++mt) {
      float pe[4];
#pragma unroll
      for (int e = 0; e < 4; ++e) pe[e] = tanhf_(Cu[mt][e] + sbk) * cxk;
#pragma unroll
      for (int mask = 1; mask < 16; mask <<= 1)
#pragma unroll
        for (int e = 0; e < 4; ++e) pe[e] += __shfl_xor(pe[e], mask, 16);
      if (l == 0) {
#pragma unroll
        for (int e = 0; e < 4; ++e)
          spart[w][a * 64 + mt * 16 + q * 4 + e] = pe[e];
      }
    }
  }
  __syncthreads();

  // phase B: s = tanh(sum over waves); softmax over a
  if (t < 256) {
    float s = spart[0][t] + spart[1][t] + spart[2][t] + spart[3][t]
            + spart[4][t] + spart[5][t] + spart[6][t] + spart[7][t];
    spart[0][t] = tanhf_(s);
  }
  __syncthreads();
  if (t < 64) {
    float s0 = spart[0][t], s1 = spart[0][64 + t], s2 = spart[0][128 + t], s3 = spart[0][192 + t];
    float m = fmaxf(fmaxf(s0, s1), fmaxf(s2, s3));
    float e0 = __expf(s0 - m), e1 = __expf(s1 - m), e2 = __expf(s2 - m), e3 = __expf(s3 - m);
    float inv = 1.0f / (e0 + e1 + e2 + e3);
    alf[t] = e0 * inv; alf[64 + t] = e1 * inv; alf[128 + t] = e2 * inv; alf[192 + t] = e3 * inv;
  }
  __syncthreads();

  // phase C: h0 = sum_a alpha * child (global re-read, L2-warm); inner P fold
#pragma unroll
  for (int i = 0; i < 2; ++i) {
    int id = t + 512 * i;
    int b = id >> 4, c = id & 15;
    const unsigned short* c0p = ch_base + b * 128 + c * 8;
    float a0 = alf[b], a1 = alf[64 + b], a2 = alf[128 + b], a3 = alf[192 + b];
    uint4 v0 = *(const uint4*)(c0p);
    uint4 v1 = *(const uint4*)(c0p + 8192);
    uint4 v2 = *(const uint4*)(c0p + 16384);
    uint4 v3 = *(const uint4*)(c0p + 24576);
    const unsigned short* e0 = (const unsigned short*)&v0;
    const unsigned short* e1 = (const unsigned short*)&v1;
    const unsigned short* e2 = (const unsigned short*)&v2;
    const unsigned short* e3 = (const unsigned short*)&v3;
    union { unsigned short u[8]; uint4 v; } o;
#pragma unroll
    for (int k = 0; k < 8; ++k)
      o.u[k] = f2b(a0 * b2f(e0[k]) + a1 * b2f(e1[k]) + a2 * b2f(e2[k]) + a3 * b2f(e3[k]));
    *(uint4*)(hs + b * 128 + ((c ^ (b & 15)) << 3)) = o.v;

    if constexpr (!LEAF_CHILD) {
      const unsigned short* pc = Pch + (size_t)(4 * p) * 8192 + b * 128 + c * 8;
      uint4 p0 = *(const uint4*)(pc);
      uint4 p1 = *(const uint4*)(pc + 8192);
      uint4 p2 = *(const uint4*)(pc + 16384);
      uint4 p3 = *(const uint4*)(pc + 24576);
      const unsigned short* f0 = (const unsigned short*)&p0;
      const unsigned short* f1 = (const unsigned short*)&p1;
      const unsigned short* f2 = (const unsigned short*)&p2;
      const unsigned short* f3 = (const unsigned short*)&p3;
#pragma unroll
      for (int k = 0; k < 8; ++k)
        rm[i][k] = fmaxf(rm[i][k],
                   fmaxf(fmaxf(b2f(f0[k]), b2f(f1[k])), fmaxf(b2f(f2[k]), b2f(f3[k]))));
    }
  }
  __syncthreads();

  // phase D: GRU. x A-frags direct from emb (L1-resident 64-row set);
  // h A-frags from hs.
  const int j = w * 16 + l;
  bf16x8 Br[8], Bz[8], Bn[4], Bh[4];
#pragma unroll
  for (int ks = 0; ks < 4; ++ks) {
    const int ko = ks * 32 + q * 8;
    Br[ks] = *(const bf16x8*)(wih + (size_t)j * 128 + ko);
    Bz[ks] = *(const bf16x8*)(wih + (size_t)(128 + j) * 128 + ko);
    Bn[ks] = *(const bf16x8*)(wih + (size_t)(256 + j) * 128 + ko);
    Br[4 + ks] = *(const bf16x8*)(whh + (size_t)j * 128 + ko);
    Bz[4 + ks] = *(const bf16x8*)(whh + (size_t)(128 + j) * 128 + ko);
    Bh[ks]     = *(const bf16x8*)(whh + (size_t)(256 + j) * 128 + ko);
  }

  f32x4 Cr[4] = {}, Cz[4] = {}, Cn[4] = {}, Ch[4] = {};
#pragma unroll
  for (int ks = 0; ks < 4; ++ks) {           // x part: direct emb gathers
    const int ko = (ks * 4 + q) * 8;
    bf16x8 A[4];
#pragma unroll
    for (int mt = 0; mt < 4; ++mt)
      A[mt] = *(const bf16x8*)(embb + (size_t)tokm[mt] * 128 + ko);
#pragma unroll
    for (int mt = 0; mt < 4; ++mt) {
      Cr[mt] = mfma16(A[mt], Br[ks], Cr[mt]);
      Cz[mt] = mfma16(A[mt], Bz[ks], Cz[mt]);
      Cn[mt] = mfma16(A[mt], Bn[ks], Cn[mt]);
    }
  }
#pragma unroll
  for (int ks = 0; ks < 4; ++ks) {           // h part: from hs LDS
    bf16x8 A[4];
#pragma unroll
    for (int mt = 0; mt < 4; ++mt) {
      int m = mt * 16 + l, c = ks * 4 + q;
      A[mt] = *(const bf16x8*)(hs + m * 128 + (((c ^ l) & 15) << 3));
    }
#pragma unroll
    for (int mt = 0; mt < 4; ++mt) {
      Cr[mt] = mfma16(A[mt], Br[4 + ks], Cr[mt]);
      Cz[mt] = mfma16(A[mt], Bz[4 + ks], Cz[mt]);
      Ch[mt] = mfma16(A[mt], Bh[ks], Ch[mt]);
    }
  }

  const float bR = b_ih[j] + b_hh[j];
  const float bZ = b_ih[128 + j] + b_hh[128 + j];
  const float bN = b_ih[256 + j];
  const float bH = b_hh[256 + j];
  const int c16 = j >> 3;

#pragma unroll
  for (int mt = 0; mt < 4; ++mt) {
#pragma unroll
    for (int e = 0; e < 4; ++e) {
      const int b = mt * 16 + q * 4 + e;
      float r  = sigm(Cr[mt][e] + bR);
      float zc = sigmc(Cz[mt][e] + bZ);
      float nv = tanhf_(Cn[mt][e] + bN + r * (Ch[mt][e] + bH));
      float hp = b2f(hs[b * 128 + (((c16 ^ (b & 15)) & 15) << 3) + (j & 7)]);
      chv[b * 136 + j] = f2b(fmaf(zc, nv - hp, hp));
    }
  }
  __syncthreads();

  // final: hout + Pout = max(hv, child subtree max), both dwordx4
#pragma unroll
  for (int i = 0; i < 2; ++i) {
    int g = t + 512 * i;
    int m = g >> 4, c = g & 15;
    uint4 v = *(const uint4*)(chv + m * 136 + c * 8);
    *(uint4*)(hout + (size_t)(p * 64 + m) * 128 + c * 8) = v;
    const unsigned short* e = (const unsigned short*)&v;
    union { unsigned short u[8]; uint4 v4; } pv;
#pragma unroll
    for (int k = 0; k < 8; ++k)
      pv.u[k] = f2b(fmaxf(rm[i][k], b2f(e[k])));   // exact: max of bf16 values
    *(uint4*)(Pout + (size_t)(p * 64 + m) * 128 + c * 8) = pv.v4;
  }
}

extern "C" void kernel_launch(void* const* d_in, const int* in_sizes, int n_in,
                              void* d_out, int out_size, void* d_ws, size_t ws_size,
                              hipStream_t stream) {
  const int*   tokens = (const int*)d_in[0];
  const float* emb    = (const float*)d_in[1];
  const float* sent_w = (const float*)d_in[2];
  const float* sent_b = (const float*)d_in[3];
  const float* ctx_w  = (const float*)d_in[4];
  const float* w_ih   = (const float*)d_in[5];
  const float* w_hh   = (const float*)d_in[6];
  const float* b_ih   = (const float*)d_in[7];
  const float* b_hh   = (const float*)d_in[8];

  char* ws = (char*)d_ws;
  unsigned short* wihb = (unsigned short*)(ws + WS_WIH);
  unsigned short* whhb = (unsigned short*)(ws + WS_WHH);
  unsigned short* swtb = (unsigned short*)(ws + WS_SWT);
  unsigned short* embb = (unsigned short*)(ws + WS_EMB);
  unsigned short* P    = (unsigned short*)(ws + WS_P);
  unsigned short* H    = (unsigned short*)(ws + WS_H);

  hipLaunchKernelGGL(prep_all, dim3(6698), dim3(256), 0, stream,
                     emb, w_ih, w_hh, sent_w, embb, wihb, whhb, swtb);

  static const int offs[7] = {0, 1, 5, 21, 85, 341, 1365};

  // leaves (d=6): P aliases H
  hipLaunchKernelGGL(gru_leaf, dim3(4096), dim3(512), 0, stream,
                     tokens + (size_t)offs[6] * 64, embb, wihb, b_ih, b_hh,
                     H + (size_t)offs[6] * 8192);

  // d=5: children are leaves (child P = child h, folded during staging)
  hipLaunchKernelGGL((fused_attn_gru<true>), dim3(1024), dim3(512), 0, stream,
                     H + (size_t)offs[6] * 8192, (const unsigned short*)nullptr,
                     tokens + (size_t)offs[5] * 64,
                     embb, wihb, whhb, swtb, sent_b, ctx_w, b_ih, b_hh,
                     H + (size_t)offs[5] * 8192, P + (size_t)offs[5] * 8192);

  // d=4..0: children are inner (explicit child-P fold)
  for (int d = 4; d >= 0; --d) {
    int n = 1 << (2 * d);
    hipLaunchKernelGGL((fused_attn_gru<false>), dim3(n), dim3(512), 0, stream,
                       H + (size_t)offs[d + 1] * 8192, P + (size_t)offs[d + 1] * 8192,
                       tokens + (size_t)offs[d] * 64,
                       embb, wihb, whhb, swtb, sent_b, ctx_w, b_ih, b_hh,
                       H + (size_t)offs[d] * 8192, P + (size_t)offs[d] * 8192);
  }

  hipLaunchKernelGGL(decode_out, dim3(32), dim3(256), 0, stream, P, (float*)d_out);
}